// Round 9
// baseline (257.728 us; speedup 1.0000x reference)
//
#include <hip/hip_runtime.h>
#include <stdint.h>

// ---- problem constants (from reference) ----
#define NS 200000      // source nodes
#define NT 20000       // target nodes
#define SD 1024        // source dim (K)
#define ED 32          // embed dim
#define TD 16          // target dim
#define NE 4000000     // edges

typedef __bf16 bf16x8 __attribute__((ext_vector_type(8)));
typedef float  f32x4  __attribute__((ext_vector_type(4)));
typedef int    i32x4  __attribute__((ext_vector_type(4)));
typedef unsigned int u32;
typedef unsigned short u16;

__device__ inline u16 f2bf_u(float f) {
    u32 u = __builtin_bit_cast(u32, f);
    u += 0x7fffu + ((u >> 16) & 1u);   // RNE
    return (u16)(u >> 16);
}

// ---------------------------------------------------------------------------
// k-bijection (shared by pfrag + proj):
//   f(g,j) = g*4 + j        for j in 0..3
//   f(g,j) = 16 + g*4 + j-4 for j in 4..7
// A and B fragments use the identical bijection -> MFMA dot exact under any
// HW k-order (slot-to-slot pairing cancels the permutation).
// ---------------------------------------------------------------------------

// Kernel 0: P = embed @ weight (fp32, [1024][16]) stored as bf16 B-fragments:
//   frag slot (kc, lane g*16+c, elem j) = P[kc*32 + f(g,j)][c]
__global__ void pfrag_kernel(const float* __restrict__ embed,
                             const float* __restrict__ weight,
                             u16* __restrict__ bfrag) {
    int tid = blockIdx.x * 256 + threadIdx.x;   // 16384 threads
    int k = tid >> 4;      // 0..1023
    int c = tid & 15;      // 0..15
    float p = 0.f;
#pragma unroll
    for (int d = 0; d < ED; ++d) p += embed[(size_t)k * ED + d] * weight[d * TD + c];
    int kc = k >> 5, r = k & 31;
    int g, j;
    if (r < 16) { g = r >> 2; j = r & 3; }
    else        { g = (r - 16) >> 2; j = 4 + ((r - 16) & 3); }
    bfrag[((size_t)(kc * 64) + g * 16 + c) * 8 + j] = f2bf_u(p);
}

// ---------------------------------------------------------------------------
// Kernel 1: x2 = bf16( (source_feat @ P) / x_norm ). Measured R5: 145.8us =
// 5.66 TB/s (90% of copy ceiling). R8: epilogue now writes two split halves
// xlo[NS][8] / xhi[NS][8] (3.2 MB each) so each agg pass's gather working
// set fits a single XCD's 4 MiB L2.
// ---------------------------------------------------------------------------
__global__ __launch_bounds__(256, 4) void proj_kernel(
    const float* __restrict__ A, const float* __restrict__ xnorm,
    const u16* __restrict__ bfrag, u16* __restrict__ xlo,
    u16* __restrict__ xhi) {
    int w = threadIdx.x >> 6;          // wave 0..3
    int l = threadIdx.x & 63;
    int m = blockIdx.x * 4 + w;        // M-tile 0..12499 (200000/16)
    int g = l >> 4, c = l & 15;

    const float* arow = A + (size_t)(m * 16 + c) * SD + g * 4;
    const i32x4* bf = (const i32x4*)bfrag + l;

    f32x4 acc = {0.f, 0.f, 0.f, 0.f};

    for (int win = 0; win < 4; ++win) {
        const float* ap = arow + win * 256;
        f32x4 av[16];
#pragma unroll
        for (int kk = 0; kk < 8; ++kk) {
            av[2 * kk]     = *(const f32x4*)(ap + kk * 32);        // bytes 0..63
            av[2 * kk + 1] = *(const f32x4*)(ap + kk * 32 + 16);   // bytes 64..127
        }
#pragma unroll
        for (int kk = 0; kk < 8; ++kk) {
            f32x4 a0 = av[2 * kk], a1 = av[2 * kk + 1];
            bf16x8 a;
            a[0] = (__bf16)a0[0]; a[1] = (__bf16)a0[1];
            a[2] = (__bf16)a0[2]; a[3] = (__bf16)a0[3];
            a[4] = (__bf16)a1[0]; a[5] = (__bf16)a1[1];
            a[6] = (__bf16)a1[2]; a[7] = (__bf16)a1[3];
            bf16x8 b = __builtin_bit_cast(bf16x8, bf[(win * 8 + kk) * 64]);
            acc = __builtin_amdgcn_mfma_f32_16x16x32_bf16(a, b, acc, 0, 0, 0);
        }
    }

    // C/D layout (HW-verified): col = lane&15, row = (lane>>4)*4 + reg
    u16* xpart = (c < 8) ? xlo : xhi;
    int cc = c & 7;
#pragma unroll
    for (int r = 0; r < 4; ++r) {
        int grow = m * 16 + g * 4 + r;
        float inv = 1.0f / xnorm[grow];
        __bf16 v = (__bf16)(acc[r] * inv);
        xpart[(size_t)grow * 8 + cc] = __builtin_bit_cast(u16, v);
    }
}

// ---------------------------------------------------------------------------
// Kernel 2: out[t][dofs..dofs+7] = mean over edge slice of an 8-dim half-row.
// Working set (xh) = 3.2 MB -> fits every XCD's 4 MiB L2 -> gathers are L2
// hits. One wave per target, 64 edges/iter, 1 lane/edge, dwordx4 (16 B row).
// ---------------------------------------------------------------------------
__global__ __launch_bounds__(256) void agg_half_kernel(
    const u16* __restrict__ xh, const int* __restrict__ edge_src,
    const int* __restrict__ range_list, float* __restrict__ out, int dofs) {
    int w = threadIdx.x >> 6, l = threadIdx.x & 63;
    int t = blockIdx.x * 4 + w;       // 5000 blocks * 4 = 20000 targets
    int start = range_list[2 * t];
    int end   = range_list[2 * t + 1];
    int deg = end - start;
    int nfull = deg >> 6;             // full 64-edge iterations (~3)
    const int* ep = edge_src + start + l;

    float acc[8];
#pragma unroll
    for (int j = 0; j < 8; ++j) acc[j] = 0.f;

    // tail id hoisted (independent chain)
    int etail = start + nfull * 64 + l;
    int sid_tail = (etail < end) ? edge_src[etail] : -1;

#pragma unroll 2
    for (int i = 0; i < nfull; ++i) {
        int sid = ep[i * 64];         // no guard: always in range
        i32x4 v = *(const i32x4*)(xh + (size_t)sid * 8);
#pragma unroll
        for (int j = 0; j < 4; ++j) {
            u32 u = (u32)v[j];
            acc[2 * j]     += __builtin_bit_cast(float, u << 16);
            acc[2 * j + 1] += __builtin_bit_cast(float, u & 0xffff0000u);
        }
    }
    if (sid_tail >= 0) {
        i32x4 v = *(const i32x4*)(xh + (size_t)sid_tail * 8);
#pragma unroll
        for (int j = 0; j < 4; ++j) {
            u32 u = (u32)v[j];
            acc[2 * j]     += __builtin_bit_cast(float, u << 16);
            acc[2 * j + 1] += __builtin_bit_cast(float, u & 0xffff0000u);
        }
    }

    // reduce across all 64 lanes (each lane = one edge's 8 dims)
#pragma unroll
    for (int m = 1; m <= 32; m <<= 1) {
#pragma unroll
        for (int j = 0; j < 8; ++j) acc[j] += __shfl_xor(acc[j], m);
    }

    if (l == 0) {
        float inv = 1.0f / (float)(deg > 0 ? deg : 1);
        f32x4 o0 = {acc[0] * inv, acc[1] * inv, acc[2] * inv, acc[3] * inv};
        f32x4 o1 = {acc[4] * inv, acc[5] * inv, acc[6] * inv, acc[7] * inv};
        float* dst = out + (size_t)t * TD + dofs;
        *(f32x4*)(dst)     = o0;
        *(f32x4*)(dst + 4) = o1;
    }
}

// ---------------------------------------------------------------------------
extern "C" void kernel_launch(void* const* d_in, const int* in_sizes, int n_in,
                              void* d_out, int out_size, void* d_ws, size_t ws_size,
                              hipStream_t stream) {
    const float* source_feat = (const float*)d_in[0];
    const float* x_norm      = (const float*)d_in[1];
    const int*   edge_index  = (const int*)d_in[2];   // row 0 = src ids
    const int*   range_list  = (const int*)d_in[3];
    const float* embed       = (const float*)d_in[4];
    const float* weight      = (const float*)d_in[5];
    float* out = (float*)d_out;

    u16* bfrag = (u16*)d_ws;                               // 32 KB
    u16* xlo   = (u16*)((char*)d_ws + 32768);              // 3.2 MB (NS*8*2)
    u16* xhi   = (u16*)((char*)d_ws + 32768 + 3200000);    // 3.2 MB

    hipLaunchKernelGGL(pfrag_kernel, dim3(64),   dim3(256), 0, stream,
                       embed, weight, bfrag);
    hipLaunchKernelGGL(proj_kernel,  dim3(3125), dim3(256), 0, stream,
                       source_feat, x_norm, bfrag, xlo, xhi);
    // R8 measurement: agg pair launched twice (idempotent, bit-identical
    // output). total ~= 155us + 2*(aggA+aggB) -> exact agg cost.
    hipLaunchKernelGGL(agg_half_kernel, dim3(5000), dim3(256), 0, stream,
                       xlo, edge_index, range_list, out, 0);
    hipLaunchKernelGGL(agg_half_kernel, dim3(5000), dim3(256), 0, stream,
                       xhi, edge_index, range_list, out, 8);
    hipLaunchKernelGGL(agg_half_kernel, dim3(5000), dim3(256), 0, stream,
                       xlo, edge_index, range_list, out, 0);
    hipLaunchKernelGGL(agg_half_kernel, dim3(5000), dim3(256), 0, stream,
                       xhi, edge_index, range_list, out, 8);
}

// Round 10
// 195.190 us; speedup vs baseline: 1.3204x; 1.3204x over previous
//
#include <hip/hip_runtime.h>
#include <stdint.h>

// ---- problem constants (from reference) ----
#define NS 200000      // source nodes
#define NT 20000       // target nodes
#define SD 1024        // source dim (K)
#define ED 32          // embed dim
#define TD 16          // target dim
#define NE 4000000     // edges

typedef __bf16 bf16x8 __attribute__((ext_vector_type(8)));
typedef float  f32x4  __attribute__((ext_vector_type(4)));
typedef int    i32x4  __attribute__((ext_vector_type(4)));
typedef unsigned int u32;
typedef unsigned short u16;

__device__ inline u16 f2bf_u(float f) {
    u32 u = __builtin_bit_cast(u32, f);
    u += 0x7fffu + ((u >> 16) & 1u);   // RNE
    return (u16)(u >> 16);
}

// ---------------------------------------------------------------------------
// k-bijection (shared by pfrag + proj):
//   f(g,j) = g*4 + j        for j in 0..3
//   f(g,j) = 16 + g*4 + j-4 for j in 4..7
// A and B fragments use the identical bijection -> MFMA dot exact under any
// HW k-order (slot-to-slot pairing cancels the permutation).
// ---------------------------------------------------------------------------

// Kernel 0: P = embed @ weight (fp32, [1024][16]) stored as bf16 B-fragments:
//   frag slot (kc, lane g*16+c, elem j) = P[kc*32 + f(g,j)][c]
__global__ void pfrag_kernel(const float* __restrict__ embed,
                             const float* __restrict__ weight,
                             u16* __restrict__ bfrag) {
    int tid = blockIdx.x * 256 + threadIdx.x;   // 16384 threads
    int k = tid >> 4;      // 0..1023
    int c = tid & 15;      // 0..15
    float p = 0.f;
#pragma unroll
    for (int d = 0; d < ED; ++d) p += embed[(size_t)k * ED + d] * weight[d * TD + c];
    int kc = k >> 5, r = k & 31;
    int g, j;
    if (r < 16) { g = r >> 2; j = r & 3; }
    else        { g = (r - 16) >> 2; j = 4 + ((r - 16) & 3); }
    bfrag[((size_t)(kc * 64) + g * 16 + c) * 8 + j] = f2bf_u(p);
}

// ---------------------------------------------------------------------------
// Kernel 1: x2 = bf16( (source_feat @ P) / x_norm ), stored [NS][16] bf16.
// Measured: 145.8us = 5.66 TB/s (90% of 6.29 TB/s copy ceiling). The 1KB/row
// hoisted-load windows (R3) are what buys the last 1.5x; bijection/line-
// coverage (R4) and occupancy (R6) were null -> residual is DRAM-side.
// ---------------------------------------------------------------------------
__global__ __launch_bounds__(256, 4) void proj_kernel(
    const float* __restrict__ A, const float* __restrict__ xnorm,
    const u16* __restrict__ bfrag, u16* __restrict__ xout) {
    int w = threadIdx.x >> 6;          // wave 0..3
    int l = threadIdx.x & 63;
    int m = blockIdx.x * 4 + w;        // M-tile 0..12499 (200000/16)
    int g = l >> 4, c = l & 15;

    const float* arow = A + (size_t)(m * 16 + c) * SD + g * 4;
    const i32x4* bf = (const i32x4*)bfrag + l;

    f32x4 acc = {0.f, 0.f, 0.f, 0.f};

    for (int win = 0; win < 4; ++win) {
        const float* ap = arow + win * 256;
        f32x4 av[16];
#pragma unroll
        for (int kk = 0; kk < 8; ++kk) {
            av[2 * kk]     = *(const f32x4*)(ap + kk * 32);        // bytes 0..63
            av[2 * kk + 1] = *(const f32x4*)(ap + kk * 32 + 16);   // bytes 64..127
        }
#pragma unroll
        for (int kk = 0; kk < 8; ++kk) {
            f32x4 a0 = av[2 * kk], a1 = av[2 * kk + 1];
            bf16x8 a;
            a[0] = (__bf16)a0[0]; a[1] = (__bf16)a0[1];
            a[2] = (__bf16)a0[2]; a[3] = (__bf16)a0[3];
            a[4] = (__bf16)a1[0]; a[5] = (__bf16)a1[1];
            a[6] = (__bf16)a1[2]; a[7] = (__bf16)a1[3];
            bf16x8 b = __builtin_bit_cast(bf16x8, bf[(win * 8 + kk) * 64]);
            acc = __builtin_amdgcn_mfma_f32_16x16x32_bf16(a, b, acc, 0, 0, 0);
        }
    }

    // C/D layout (HW-verified): col = lane&15, row = (lane>>4)*4 + reg
#pragma unroll
    for (int r = 0; r < 4; ++r) {
        int grow = m * 16 + g * 4 + r;
        float inv = 1.0f / xnorm[grow];
        __bf16 v = (__bf16)(acc[r] * inv);
        xout[(size_t)grow * TD + c] = __builtin_bit_cast(u16, v);
    }
}

// ---------------------------------------------------------------------------
// Kernel 2: out[t] = mean over edge slice of x2 rows (edges target-sorted).
// ~40us = request-rate floor: 4M random line requests @ ~6 cyc/edge/CU
// (invariant under issue shape, row bytes 64/32/16B, MLP depth, and working-
// set size 6.4/3.2MB — probed R1/R2/R7/R8). One wave per target, 32
// edges/iter (2 lanes/edge, dwordx4), guard-free full iters + hoisted tail.
// ---------------------------------------------------------------------------
__global__ __launch_bounds__(256) void agg_kernel(
    const u16* __restrict__ xbf, const int* __restrict__ edge_src,
    const int* __restrict__ range_list, float* __restrict__ out) {
    int w = threadIdx.x >> 6, l = threadIdx.x & 63;
    int t = blockIdx.x * 4 + w;       // 5000 blocks * 4 = 20000 targets
    int start = range_list[2 * t];
    int end   = range_list[2 * t + 1];
    int grp = l >> 1;                 // 0..31: edge slot within iteration
    int hd  = l & 1;                  // half-row: dims hd*8 .. hd*8+7

    float acc[8];
#pragma unroll
    for (int j = 0; j < 8; ++j) acc[j] = 0.f;

    int deg = end - start;
    int nfull = deg >> 5;             // full 32-edge iterations
    const int* ep = edge_src + start + grp;

    // tail id hoisted: issues before the main loop, independent chain
    int etail = start + nfull * 32 + grp;
    int sid_tail = (etail < end) ? edge_src[etail] : -1;

#pragma unroll 4
    for (int i = 0; i < nfull; ++i) {
        int sid = ep[i * 32];         // no guard: always in range
        i32x4 v = *(const i32x4*)(xbf + (size_t)sid * TD + hd * 8);
#pragma unroll
        for (int j = 0; j < 4; ++j) {
            u32 u = (u32)v[j];
            acc[2 * j]     += __builtin_bit_cast(float, u << 16);
            acc[2 * j + 1] += __builtin_bit_cast(float, u & 0xffff0000u);
        }
    }
    // tail
    if (sid_tail >= 0) {
        i32x4 v = *(const i32x4*)(xbf + (size_t)sid_tail * TD + hd * 8);
#pragma unroll
        for (int j = 0; j < 4; ++j) {
            u32 u = (u32)v[j];
            acc[2 * j]     += __builtin_bit_cast(float, u << 16);
            acc[2 * j + 1] += __builtin_bit_cast(float, u & 0xffff0000u);
        }
    }

    // reduce over the 32 edge-groups (xor 2,4,8,16,32)
#pragma unroll
    for (int m = 2; m <= 32; m <<= 1) {
#pragma unroll
        for (int j = 0; j < 8; ++j) acc[j] += __shfl_xor(acc[j], m);
    }

    if (l < 2) {                      // lane 0: dims 0-7, lane 1: dims 8-15
        float inv = 1.0f / (float)(deg > 0 ? deg : 1);
        f32x4 o0 = {acc[0] * inv, acc[1] * inv, acc[2] * inv, acc[3] * inv};
        f32x4 o1 = {acc[4] * inv, acc[5] * inv, acc[6] * inv, acc[7] * inv};
        float* dst = out + (size_t)t * TD + hd * 8;
        *(f32x4*)(dst)     = o0;
        *(f32x4*)(dst + 4) = o1;
    }
}

// ---------------------------------------------------------------------------
extern "C" void kernel_launch(void* const* d_in, const int* in_sizes, int n_in,
                              void* d_out, int out_size, void* d_ws, size_t ws_size,
                              hipStream_t stream) {
    const float* source_feat = (const float*)d_in[0];
    const float* x_norm      = (const float*)d_in[1];
    const int*   edge_index  = (const int*)d_in[2];   // row 0 = src ids
    const int*   range_list  = (const int*)d_in[3];
    const float* embed       = (const float*)d_in[4];
    const float* weight      = (const float*)d_in[5];
    float* out = (float*)d_out;

    u16* bfrag = (u16*)d_ws;                               // 32 KB
    u16* xbf   = (u16*)((char*)d_ws + 32768);              // 6.4 MB (NS*16*2)

    hipLaunchKernelGGL(pfrag_kernel, dim3(64),   dim3(256), 0, stream,
                       embed, weight, bfrag);
    hipLaunchKernelGGL(proj_kernel,  dim3(3125), dim3(256), 0, stream,
                       source_feat, x_norm, bfrag, xbf);
    hipLaunchKernelGGL(agg_kernel,   dim3(5000), dim3(256), 0, stream,
                       xbf, edge_index, range_list, out);
}